// Round 1
// baseline (167.528 us; speedup 1.0000x reference)
//
#include <hip/hip_runtime.h>
#include <hip/hip_bf16.h>
#include <stdint.h>

typedef __bf16 bf16_t;
typedef __bf16 bf16x8 __attribute__((ext_vector_type(8)));
typedef float  f32x4  __attribute__((ext_vector_type(4)));

#define AS1 __attribute__((address_space(1)))
#define AS3 __attribute__((address_space(3)))

__device__ __forceinline__ void gload16(const bf16_t* g, char* l) {
  // global -> LDS direct, 16B per lane. LDS dest: wave-uniform base + lane*16.
  __builtin_amdgcn_global_load_lds((AS1 const void*)(uintptr_t)g, (AS3 void*)l, 16, 0, 0);
}

// ---------------- f32 -> bf16 convert (vectorized) ----------------
__global__ void cvt_f32_bf16(const float* __restrict__ in, bf16_t* __restrict__ out, int n4) {
  int i = blockIdx.x * blockDim.x + threadIdx.x;
  if (i >= n4) return;
  float4 v = reinterpret_cast<const float4*>(in)[i];
  union { bf16_t h[4]; unsigned long long u; } r;
  r.h[0] = (bf16_t)v.x; r.h[1] = (bf16_t)v.y; r.h[2] = (bf16_t)v.z; r.h[3] = (bf16_t)v.w;
  reinterpret_cast<unsigned long long*>(out)[i] = r.u;
}

// ---------------- W[K][N] f32 -> Wt[N][K] bf16 (tiled transpose) ----------------
__global__ void trans_cvt(const float* __restrict__ W, bf16_t* __restrict__ Wt, int K, int N) {
  __shared__ float tile[32][33];
  const int kb = blockIdx.x * 32, nb = blockIdx.y * 32;
  const int tx = threadIdx.x, ty = threadIdx.y;
#pragma unroll
  for (int i = 0; i < 32; i += 8)
    tile[ty + i][tx] = W[(size_t)(kb + ty + i) * N + nb + tx];
  __syncthreads();
#pragma unroll
  for (int i = 0; i < 32; i += 8)
    Wt[(size_t)(nb + ty + i) * K + kb + tx] = (bf16_t)tile[tx][ty + i];
}

// ---------------- V^T per head: vT[bh][d][t] = qkv[b*2048+t][2048+h*64+d] ----------------
__global__ void vtrans(const bf16_t* __restrict__ qkv, bf16_t* __restrict__ vT) {
  __shared__ bf16_t tile[32][33];
  const int tb = blockIdx.x * 32;   // t block (2048/32)
  const int db = blockIdx.y * 32;   // d block (64/32)
  const int bh = blockIdx.z;        // b*16+h
  const int b = bh >> 4, h = bh & 15;
  const int tx = threadIdx.x, ty = threadIdx.y;
#pragma unroll
  for (int i = 0; i < 32; i += 8)
    tile[ty + i][tx] = qkv[(size_t)(b * 2048 + tb + ty + i) * 3072 + 2048 + h * 64 + db + tx];
  __syncthreads();
#pragma unroll
  for (int i = 0; i < 32; i += 8)
    vT[(size_t)bh * 131072 + (size_t)(db + ty + i) * 2048 + tb + tx] = tile[tx][ty + i];
}

// ---------------- GEMM: C[M][N] = A[M][K] @ Bt[N][K]^T + bias ----------------
// 128x128 tile, BK=32, 4 waves (2x2), 16x16x32 bf16 MFMA, 4x4 frags/wave.
// LDS tiles [128][32] bf16, row stride 64B, XOR-swizzle byte ^= ((row>>1)&3)<<4
// (linear LDS dest for global_load_lds; swizzle applied via pre-swizzled SOURCE col).
__global__ __launch_bounds__(256) void gemm_bt(
    const bf16_t* __restrict__ A, const bf16_t* __restrict__ Bt,
    const float* __restrict__ bias,
    bf16_t* __restrict__ outb, float* __restrict__ outf,
    int M, int N, int K, int f32_out) {
  __shared__ bf16_t lA[128 * 32];
  __shared__ bf16_t lB[128 * 32];
  const int tid = threadIdx.x;
  const int wave = tid >> 6, lane = tid & 63;
  const int lr = lane & 15, lg = lane >> 4;
  const int ntiles = N >> 7;
  const int bn = blockIdx.x % ntiles, bm = blockIdx.x / ntiles;
  const int m0 = bm * 128, n0 = bn * 128;
  const int wr = wave >> 1, wc = wave & 1;
  f32x4 acc[4][4] = {};

  for (int k0 = 0; k0 < K; k0 += 32) {
    __syncthreads();  // all waves done reading previous tiles
#pragma unroll
    for (int it = 0; it < 2; ++it) {
      const int wbase = it * 256 + wave * 64;     // wave-uniform chunk base
      const int lam = wbase + lane;               // chunk 0..511
      const int row = lam >> 2;                   // 4 chunks per 64B row
      const int colb = ((lam & 3) << 4) ^ (((row >> 1) & 3) << 4);
      gload16(A  + (size_t)(m0 + row) * K + k0 + (colb >> 1), (char*)lA + wbase * 16);
      gload16(Bt + (size_t)(n0 + row) * K + k0 + (colb >> 1), (char*)lB + wbase * 16);
    }
    __syncthreads();  // drains vmcnt before barrier

    bf16x8 af[4], bfv[4];
#pragma unroll
    for (int mi = 0; mi < 4; ++mi) {
      const int row = wr * 64 + mi * 16 + lr;
      af[mi] = *reinterpret_cast<const bf16x8*>(
          (const char*)lA + row * 64 + ((lg * 16) ^ (((row >> 1) & 3) << 4)));
    }
#pragma unroll
    for (int ni = 0; ni < 4; ++ni) {
      const int row = wc * 64 + ni * 16 + lr;
      bfv[ni] = *reinterpret_cast<const bf16x8*>(
          (const char*)lB + row * 64 + ((lg * 16) ^ (((row >> 1) & 3) << 4)));
    }
#pragma unroll
    for (int mi = 0; mi < 4; ++mi)
#pragma unroll
      for (int ni = 0; ni < 4; ++ni)
        acc[mi][ni] = __builtin_amdgcn_mfma_f32_16x16x32_bf16(af[mi], bfv[ni], acc[mi][ni], 0, 0, 0);
  }

  // epilogue: D layout col = lane&15, row = (lane>>4)*4 + reg
#pragma unroll
  for (int mi = 0; mi < 4; ++mi) {
#pragma unroll
    for (int ni = 0; ni < 4; ++ni) {
      const int col = n0 + wc * 64 + ni * 16 + lr;
      const float bv = bias[col];
#pragma unroll
      for (int r = 0; r < 4; ++r) {
        const int rowg = m0 + wr * 64 + mi * 16 + lg * 4 + r;
        const float v = acc[mi][ni][r] + bv;
        if (f32_out) outf[(size_t)rowg * N + col] = v;
        else         outb[(size_t)rowg * N + col] = (bf16_t)v;
      }
    }
  }
}

// ---------------- Flash attention (no mask), scale = 1/sqrt(H) = 0.25 ----------------
// Grid: (qblocks=32, bh=32). Block: 256 thr = 4 waves, each wave 16 q-rows.
// Swapped QK^T: S^T = mfma(A=K_rows, B=Q^T). Key-permutation per 16-tile:
//   tile0 coord c -> key 8*(c>>2)+(c&3) ; tile1 -> +4  => S^T output regs are
//   identity-mapped into the PV A-fragment (slot = actual key), no shuffles.
__global__ __launch_bounds__(256) void attn_fwd(
    const bf16_t* __restrict__ qkv,   // [4096][3072]
    const bf16_t* __restrict__ vT,    // [32][64][2048]
    bf16_t* __restrict__ aout) {      // [4096][1024]
  __shared__ bf16_t lK[32 * 64];      // [32 keys][64 d]  (128B rows, swizzled)
  __shared__ bf16_t lV[64 * 32];      // [64 d][32 keys]  (64B rows, swizzled)
  const int tid = threadIdx.x;
  const int wave = tid >> 6, lane = tid & 63;
  const int lr = lane & 15, lg = lane >> 4;
  const int qb = blockIdx.x, bh = blockIdx.y;
  const int b = bh >> 4, h = bh & 15;

  const int qrow = qb * 64 + wave * 16 + lr;
  const size_t qoff = (size_t)(b * 2048 + qrow) * 3072 + h * 64;
  const bf16x8 qf0 = *reinterpret_cast<const bf16x8*>(qkv + qoff + 0  + lg * 8);
  const bf16x8 qf1 = *reinterpret_cast<const bf16x8*>(qkv + qoff + 32 + lg * 8);

  const bf16_t* Kbase = qkv + (size_t)(b * 2048) * 3072 + 1024 + h * 64;
  const bf16_t* Vbase = vT + (size_t)bh * 131072;

  f32x4 acc[4] = {};                 // acc[nc][r] = O[lg*4+r][nc*16+lr]
  float m = -1e30f, l = 0.f;
  const int r0 = ((lr >> 2) << 3) | (lr & 3);   // perm0 row for A-frag
  const int r1 = r0 + 4;                        // perm1 row

  for (int kb = 0; kb < 64; ++kb) {
    {
      // stage K tile: 256 chunks of 16B (8 per 128B row)
      const int krow = tid >> 3;
      const int ksw = ((krow & 3) | (((krow >> 3) & 1) << 2)) << 4;
      const int kcolb = ((tid & 7) << 4) ^ ksw;
      gload16(Kbase + (size_t)(kb * 32 + krow) * 3072 + (kcolb >> 1), (char*)lK + wave * 1024);
      // stage V^T tile: 256 chunks (4 per 64B row)
      const int vrow = tid >> 2;
      const int vcolb = ((tid & 3) << 4) ^ (((vrow >> 1) & 3) << 4);
      gload16(Vbase + (size_t)vrow * 2048 + kb * 32 + (vcolb >> 1), (char*)lV + wave * 1024);
    }
    __syncthreads();

    // K fragments (A-operand): row*128 + ((hk*64 + lg*16) ^ swzK(row)<<4)
    const int sw0 = ((r0 & 3) | (((r0 >> 3) & 1) << 2)) << 4;
    const int sw1 = ((r1 & 3) | (((r1 >> 3) & 1) << 2)) << 4;
    const bf16x8 k0lo = *reinterpret_cast<const bf16x8*>((const char*)lK + r0 * 128 + ((0  + lg * 16) ^ sw0));
    const bf16x8 k0hi = *reinterpret_cast<const bf16x8*>((const char*)lK + r0 * 128 + ((64 + lg * 16) ^ sw0));
    const bf16x8 k1lo = *reinterpret_cast<const bf16x8*>((const char*)lK + r1 * 128 + ((0  + lg * 16) ^ sw1));
    const bf16x8 k1hi = *reinterpret_cast<const bf16x8*>((const char*)lK + r1 * 128 + ((64 + lg * 16) ^ sw1));

    f32x4 s0 = {0.f, 0.f, 0.f, 0.f}, s1 = {0.f, 0.f, 0.f, 0.f};
    s0 = __builtin_amdgcn_mfma_f32_16x16x32_bf16(k0lo, qf0, s0, 0, 0, 0);
    s0 = __builtin_amdgcn_mfma_f32_16x16x32_bf16(k0hi, qf1, s0, 0, 0, 0);
    s1 = __builtin_amdgcn_mfma_f32_16x16x32_bf16(k1lo, qf0, s1, 0, 0, 0);
    s1 = __builtin_amdgcn_mfma_f32_16x16x32_bf16(k1hi, qf1, s1, 0, 0, 0);

    float p[8];
#pragma unroll
    for (int r = 0; r < 4; ++r) { p[r] = s0[r] * 0.25f; p[4 + r] = s1[r] * 0.25f; }

    float bm = p[0];
#pragma unroll
    for (int j = 1; j < 8; ++j) bm = fmaxf(bm, p[j]);
    bm = fmaxf(bm, __shfl_xor(bm, 16));
    bm = fmaxf(bm, __shfl_xor(bm, 32));
    const float mnew = fmaxf(m, bm);
    const float alpha = __expf(m - mnew);
    m = mnew;
    float bs = 0.f;
#pragma unroll
    for (int j = 0; j < 8; ++j) { p[j] = __expf(p[j] - mnew); bs += p[j]; }
    bs += __shfl_xor(bs, 16);
    bs += __shfl_xor(bs, 32);
    l = l * alpha + bs;

    // rescale O rows by per-row alpha (row q = lg*4+r lives in lane lg*4+r's state)
#pragma unroll
    for (int r = 0; r < 4; ++r) {
      const float ar = __shfl(alpha, lg * 4 + r);
      acc[0][r] *= ar; acc[1][r] *= ar; acc[2][r] *= ar; acc[3][r] *= ar;
    }

    bf16x8 pa;
#pragma unroll
    for (int j = 0; j < 8; ++j) pa[j] = (bf16_t)p[j];

#pragma unroll
    for (int nc = 0; nc < 4; ++nc) {
      const int row = nc * 16 + lr;
      const bf16x8 vf = *reinterpret_cast<const bf16x8*>(
          (const char*)lV + row * 64 + ((lg * 16) ^ (((row >> 1) & 3) << 4)));
      acc[nc] = __builtin_amdgcn_mfma_f32_16x16x32_bf16(pa, vf, acc[nc], 0, 0, 0);
    }
    __syncthreads();
  }

  const float linv = 1.f / l;
#pragma unroll
  for (int r = 0; r < 4; ++r) {
    const float lf = __shfl(linv, lg * 4 + r);
    const int qg = qb * 64 + wave * 16 + lg * 4 + r;
#pragma unroll
    for (int nc = 0; nc < 4; ++nc)
      aout[(size_t)(b * 2048 + qg) * 1024 + h * 64 + nc * 16 + lr] = (bf16_t)(acc[nc][r] * lf);
  }
}

extern "C" void kernel_launch(void* const* d_in, const int* in_sizes, int n_in,
                              void* d_out, int out_size, void* d_ws, size_t ws_size,
                              hipStream_t stream) {
  (void)in_sizes; (void)n_in; (void)out_size; (void)ws_size;
  const float* x    = (const float*)d_in[0];
  const float* Wqkv = (const float*)d_in[1];
  const float* bqkv = (const float*)d_in[2];
  const float* Wout = (const float*)d_in[3];
  const float* bout = (const float*)d_in[4];
  float* out = (float*)d_out;

  char* ws = (char*)d_ws;
  bf16_t* xb    = (bf16_t*)(ws);                 //  8.39 MB  [4096][1024]
  bf16_t* wqkvT = (bf16_t*)(ws + 8388608);       //  6.29 MB  [3072][1024]
  bf16_t* woutT = (bf16_t*)(ws + 14680064);      //  2.10 MB  [1024][1024]
  bf16_t* qkv   = (bf16_t*)(ws + 16777216);      // 25.17 MB  [4096][3072]
  bf16_t* vT    = (bf16_t*)(ws + 41943040);      //  8.39 MB  [32][64][2048]
  bf16_t* aout  = (bf16_t*)(ws + 50331648);      //  8.39 MB  [4096][1024]

  cvt_f32_bf16<<<4096, 256, 0, stream>>>(x, xb, 1048576);
  trans_cvt<<<dim3(32, 96), dim3(32, 8), 0, stream>>>(Wqkv, wqkvT, 1024, 3072);
  trans_cvt<<<dim3(32, 32), dim3(32, 8), 0, stream>>>(Wout, woutT, 1024, 1024);
  gemm_bt<<<768, 256, 0, stream>>>(xb, wqkvT, bqkv, qkv, nullptr, 4096, 3072, 1024, 0);
  vtrans<<<dim3(64, 2, 32), dim3(32, 8), 0, stream>>>(qkv, vT);
  attn_fwd<<<dim3(32, 32), 256, 0, stream>>>(qkv, vT, aout);
  gemm_bt<<<256, 256, 0, stream>>>(aout, woutT, bout, nullptr, out, 4096, 1024, 1024, 1);
}

// Round 2
// 131.863 us; speedup vs baseline: 1.2705x; 1.2705x over previous
//
#include <hip/hip_runtime.h>
#include <hip/hip_bf16.h>
#include <stdint.h>

typedef __bf16 bf16_t;
typedef __bf16 bf16x8 __attribute__((ext_vector_type(8)));
typedef float  f32x4  __attribute__((ext_vector_type(4)));

#define AS1 __attribute__((address_space(1)))
#define AS3 __attribute__((address_space(3)))

__device__ __forceinline__ void gload16(const bf16_t* g, char* l) {
  // global -> LDS direct, 16B per lane. LDS dest: wave-uniform base + lane*16.
  __builtin_amdgcn_global_load_lds((AS1 const void*)(uintptr_t)g, (AS3 void*)l, 16, 0, 0);
}
__device__ __forceinline__ int swz8(int r) { return (r & 7) ^ ((r >> 2) & 6); }

// ---------------- f32 -> bf16 convert (vectorized) ----------------
__global__ void cvt_f32_bf16(const float* __restrict__ in, bf16_t* __restrict__ out, int n4) {
  int i = blockIdx.x * blockDim.x + threadIdx.x;
  if (i >= n4) return;
  float4 v = reinterpret_cast<const float4*>(in)[i];
  union { bf16_t h[4]; unsigned long long u; } r;
  r.h[0] = (bf16_t)v.x; r.h[1] = (bf16_t)v.y; r.h[2] = (bf16_t)v.z; r.h[3] = (bf16_t)v.w;
  reinterpret_cast<unsigned long long*>(out)[i] = r.u;
}

// ---------------- W[K][N] f32 -> Wt[N][K] bf16 (tiled transpose) ----------------
__global__ void trans_cvt(const float* __restrict__ W, bf16_t* __restrict__ Wt, int K, int N) {
  __shared__ float tile[32][33];
  const int kb = blockIdx.x * 32, nb = blockIdx.y * 32;
  const int tx = threadIdx.x, ty = threadIdx.y;
#pragma unroll
  for (int i = 0; i < 32; i += 8)
    tile[ty + i][tx] = W[(size_t)(kb + ty + i) * N + nb + tx];
  __syncthreads();
#pragma unroll
  for (int i = 0; i < 32; i += 8)
    Wt[(size_t)(nb + ty + i) * K + kb + tx] = (bf16_t)tile[tx][ty + i];
}

// ---------------- GEMM: C[M][N] = A[M][K] @ Bt[N][K]^T + bias ----------------
// mode 0: bf16 out; mode 1: qkv-split (cols<2048 -> outb, cols>=2048 -> vT packed);
// mode 2: f32 out.
__global__ __launch_bounds__(256) void gemm_bt(
    const bf16_t* __restrict__ A, const bf16_t* __restrict__ Bt,
    const float* __restrict__ bias,
    bf16_t* __restrict__ outb, bf16_t* __restrict__ vtb, float* __restrict__ outf,
    int M, int N, int K, int mode) {
  __shared__ bf16_t lA[128 * 32];
  __shared__ bf16_t lB[128 * 32];
  const int tid = threadIdx.x;
  const int wave = tid >> 6, lane = tid & 63;
  const int lr = lane & 15, lg = lane >> 4;
  const int ntiles = N >> 7;
  const int bn = blockIdx.x % ntiles, bm = blockIdx.x / ntiles;
  const int m0 = bm * 128, n0 = bn * 128;
  const int wr = wave >> 1, wc = wave & 1;
  f32x4 acc[4][4] = {};

  for (int k0 = 0; k0 < K; k0 += 32) {
    __syncthreads();
#pragma unroll
    for (int it = 0; it < 2; ++it) {
      const int wbase = it * 256 + wave * 64;
      const int lam = wbase + lane;
      const int row = lam >> 2;
      const int colb = ((lam & 3) << 4) ^ (((row >> 1) & 3) << 4);
      gload16(A  + (size_t)(m0 + row) * K + k0 + (colb >> 1), (char*)lA + wbase * 16);
      gload16(Bt + (size_t)(n0 + row) * K + k0 + (colb >> 1), (char*)lB + wbase * 16);
    }
    __syncthreads();

    bf16x8 af[4], bfv[4];
#pragma unroll
    for (int mi = 0; mi < 4; ++mi) {
      const int row = wr * 64 + mi * 16 + lr;
      af[mi] = *reinterpret_cast<const bf16x8*>(
          (const char*)lA + row * 64 + ((lg * 16) ^ (((row >> 1) & 3) << 4)));
    }
#pragma unroll
    for (int ni = 0; ni < 4; ++ni) {
      const int row = wc * 64 + ni * 16 + lr;
      bfv[ni] = *reinterpret_cast<const bf16x8*>(
          (const char*)lB + row * 64 + ((lg * 16) ^ (((row >> 1) & 3) << 4)));
    }
    __builtin_amdgcn_s_setprio(1);
#pragma unroll
    for (int mi = 0; mi < 4; ++mi)
#pragma unroll
      for (int ni = 0; ni < 4; ++ni)
        acc[mi][ni] = __builtin_amdgcn_mfma_f32_16x16x32_bf16(af[mi], bfv[ni], acc[mi][ni], 0, 0, 0);
    __builtin_amdgcn_s_setprio(0);
  }

  // epilogue: D layout col = lane&15, row = (lane>>4)*4 + reg
#pragma unroll
  for (int mi = 0; mi < 4; ++mi) {
#pragma unroll
    for (int ni = 0; ni < 4; ++ni) {
      const int col = n0 + wc * 64 + ni * 16 + lr;
      const float bv = bias[col];
      const int rg0 = m0 + wr * 64 + mi * 16 + lg * 4;
      if (mode == 1 && col >= 2048) {
        // V column -> write transposed per-head: vT[b*16+h][d][t], 4 t packed (8B)
        const int colv = col - 2048;
        const int dd = colv & 63, hh = colv >> 6;
        const int bb = rg0 >> 11, t = rg0 & 2047;
        union { bf16_t h4[4]; unsigned long long u; } pk;
#pragma unroll
        for (int r = 0; r < 4; ++r) pk.h4[r] = (bf16_t)(acc[mi][ni][r] + bv);
        *reinterpret_cast<unsigned long long*>(
            vtb + (size_t)(bb * 16 + hh) * 131072 + (size_t)dd * 2048 + t) = pk.u;
      } else {
#pragma unroll
        for (int r = 0; r < 4; ++r) {
          const int rowg = rg0 + r;
          const float v = acc[mi][ni][r] + bv;
          if (mode == 2) outf[(size_t)rowg * N + col] = v;
          else           outb[(size_t)rowg * N + col] = (bf16_t)v;
        }
      }
    }
  }
}

// ---------------- Flash attention (no mask), scale = 1/sqrt(H) = 0.25 ----------------
// Grid: 512 blocks (16 qb x 32 bh, XCD-swizzled). Block: 256 thr = 4 waves,
// each wave 32 q-rows (2 halves of 16). KVBLK=64, double-buffered LDS,
// one barrier/iter. Swapped QK^T with key-permutation such that S^T output
// registers identity-map into the PV A-fragment. exp2-domain online softmax
// with defer-max (THR=8 in log2 units).
__global__ __launch_bounds__(256) void attn_fwd(
    const bf16_t* __restrict__ qkv,   // [4096][3072]
    const bf16_t* __restrict__ vT,    // [32][64][2048]
    bf16_t* __restrict__ aout) {      // [4096][1024]
  __shared__ bf16_t lds[2][8192];     // per buf: K [64k][64d] 8KB, V^T [64d][64k] 8KB
  const int tid = threadIdx.x;
  const int wave = tid >> 6, lane = tid & 63;
  const int lr = lane & 15, lg = lane >> 4;
  // XCD-aware swizzle: each XCD owns 4 heads' K/V (2MB -> L2-resident)
  const int id = blockIdx.x;
  const int xcd = id & 7, slot = id >> 3;
  const int bh = xcd * 4 + (slot & 3), qb = slot >> 2;
  const int b = bh >> 4, h = bh & 15;

  // Q fragments (B-operand): col=lr -> q-row, k=lg*8+j -> d
  const int q0 = qb * 128 + wave * 32;
  const bf16_t* Qp = qkv + (size_t)(b * 2048 + q0) * 3072 + h * 64;
  bf16x8 qf[2][2];
#pragma unroll
  for (int hx = 0; hx < 2; ++hx) {
    qf[hx][0] = *reinterpret_cast<const bf16x8*>(Qp + (size_t)(hx * 16 + lr) * 3072 + lg * 8);
    qf[hx][1] = *reinterpret_cast<const bf16x8*>(Qp + (size_t)(hx * 16 + lr) * 3072 + 32 + lg * 8);
  }

  // staging addresses (per-lane, loop-invariant except scalar advance)
  const int kr0 = tid >> 3;                         // rows 0..31
  const int ks  = (tid & 7) ^ swz8(kr0);            // swz8(kr0+32)==swz8(kr0)
  const bf16_t* Ks0 = qkv + (size_t)(b * 2048 + kr0) * 3072 + 1024 + h * 64 + ks * 8;
  const bf16_t* Ks1 = Ks0 + (size_t)32 * 3072;
  const bf16_t* Vs0 = vT + (size_t)bh * 131072 + (size_t)kr0 * 2048 + ks * 8;
  const bf16_t* Vs1 = Vs0 + (size_t)32 * 2048;

  auto stage = [&](int buf, int kb) {
    char* base = (char*)&lds[buf][0] + wave * 1024;
    gload16(Ks0 + (size_t)kb * 196608, base);
    gload16(Ks1 + (size_t)kb * 196608, base + 4096);
    gload16(Vs0 + (size_t)kb * 64, base + 8192);
    gload16(Vs1 + (size_t)kb * 64, base + 12288);
  };

  f32x4 acc[2][4] = {};          // acc[half][nc][r]: O[row=lg*4+r][d=nc*16+lr]
  float m2[2] = {-1e30f, -1e30f}, l[2] = {0.f, 0.f};
  const float c2 = 0.25f * 1.44269504f;   // scale * log2(e)

  int cur = 0;
  stage(0, 0);
  __syncthreads();

  for (int kb = 0; kb < 32; ++kb) {
    if (kb < 31) stage(cur ^ 1, kb + 1);
    const char* bK = (const char*)&lds[cur][0];
    const char* bV = bK + 8192;

    // K fragments (A-operand), key row kk = k(t, lr)
    bf16x8 kf[4][2];
#pragma unroll
    for (int t = 0; t < 4; ++t) {
      const int kk = 32 * (t >> 1) + 8 * (lr >> 2) + 4 * (t & 1) + (lr & 3);
      const int sw = swz8(kk) << 4;
      kf[t][0] = *reinterpret_cast<const bf16x8*>(bK + (kk << 7) + ((lg * 16) ^ sw));
      kf[t][1] = *reinterpret_cast<const bf16x8*>(bK + (kk << 7) + ((64 + lg * 16) ^ sw));
    }

    f32x4 s[2][4];
    __builtin_amdgcn_s_setprio(1);
#pragma unroll
    for (int hx = 0; hx < 2; ++hx)
#pragma unroll
      for (int t = 0; t < 4; ++t) {
        f32x4 z = {0.f, 0.f, 0.f, 0.f};
        z = __builtin_amdgcn_mfma_f32_16x16x32_bf16(kf[t][0], qf[hx][0], z, 0, 0, 0);
        s[hx][t] = __builtin_amdgcn_mfma_f32_16x16x32_bf16(kf[t][1], qf[hx][1], z, 0, 0, 0);
      }
    __builtin_amdgcn_s_setprio(0);

    // V fragments (B-operand) — issue before softmax so latency hides under VALU
    bf16x8 vf[4][2];
#pragma unroll
    for (int nc = 0; nc < 4; ++nc) {
      const int vr = nc * 16 + lr;
      const int sw = swz8(vr) << 4;
      vf[nc][0] = *reinterpret_cast<const bf16x8*>(bV + (vr << 7) + ((lg * 16) ^ sw));
      vf[nc][1] = *reinterpret_cast<const bf16x8*>(bV + (vr << 7) + ((64 + lg * 16) ^ sw));
    }

    // block max per half (log2 domain)
    float bm[2];
#pragma unroll
    for (int hx = 0; hx < 2; ++hx) {
      f32x4 mx = s[hx][0];
#pragma unroll
      for (int t = 1; t < 4; ++t)
#pragma unroll
        for (int r = 0; r < 4; ++r) mx[r] = fmaxf(mx[r], s[hx][t][r]);
      float v = fmaxf(fmaxf(mx[0], mx[1]), fmaxf(mx[2], mx[3])) * c2;
      v = fmaxf(v, __shfl_xor(v, 16));
      v = fmaxf(v, __shfl_xor(v, 32));
      bm[hx] = v;
    }

    // defer-max: rescale only when block max exceeds running max by >8 (log2)
    if (__any((bm[0] > m2[0] + 8.f) || (bm[1] > m2[1] + 8.f))) {
#pragma unroll
      for (int hx = 0; hx < 2; ++hx) {
        const float nm = fmaxf(m2[hx], bm[hx]);
        const float al = __builtin_amdgcn_exp2f(m2[hx] - nm);
        m2[hx] = nm; l[hx] *= al;
#pragma unroll
        for (int r = 0; r < 4; ++r) {
          const float ar = __shfl(al, lg * 4 + r);
#pragma unroll
          for (int nc = 0; nc < 4; ++nc) acc[hx][nc][r] *= ar;
        }
      }
    }

    // p = exp2(s*c2 - m2), row-sum, pack to bf16 PV A-fragments
    bf16x8 pa[2][2];
#pragma unroll
    for (int hx = 0; hx < 2; ++hx) {
      const float negm = -m2[hx];
      float p[16];
#pragma unroll
      for (int t = 0; t < 4; ++t)
#pragma unroll
        for (int r = 0; r < 4; ++r)
          p[t * 4 + r] = __builtin_amdgcn_exp2f(__builtin_fmaf(s[hx][t][r], c2, negm));
      float p0 = 0.f, p1 = 0.f, p2 = 0.f, p3 = 0.f;
#pragma unroll
      for (int j = 0; j < 4; ++j) { p0 += p[j]; p1 += p[4 + j]; p2 += p[8 + j]; p3 += p[12 + j]; }
      float sum = (p0 + p1) + (p2 + p3);
      sum += __shfl_xor(sum, 16);
      sum += __shfl_xor(sum, 32);
      l[hx] += sum;
#pragma unroll
      for (int j = 0; j < 8; ++j) { pa[hx][0][j] = (bf16_t)p[j]; pa[hx][1][j] = (bf16_t)p[8 + j]; }
    }

    __builtin_amdgcn_s_setprio(1);
#pragma unroll
    for (int hx = 0; hx < 2; ++hx)
#pragma unroll
      for (int nc = 0; nc < 4; ++nc) {
        acc[hx][nc] = __builtin_amdgcn_mfma_f32_16x16x32_bf16(pa[hx][0], vf[nc][0], acc[hx][nc], 0, 0, 0);
        acc[hx][nc] = __builtin_amdgcn_mfma_f32_16x16x32_bf16(pa[hx][1], vf[nc][1], acc[hx][nc], 0, 0, 0);
      }
    __builtin_amdgcn_s_setprio(0);

    __syncthreads();
    cur ^= 1;
  }

  // normalize + store
#pragma unroll
  for (int hx = 0; hx < 2; ++hx) {
    const float li = 1.f / l[hx];
#pragma unroll
    for (int r = 0; r < 4; ++r) {
      const float lf = __shfl(li, lg * 4 + r);
      const int qg = q0 + hx * 16 + lg * 4 + r;
      bf16_t* op = aout + (size_t)(b * 2048 + qg) * 1024 + h * 64 + lr;
#pragma unroll
      for (int nc = 0; nc < 4; ++nc) op[nc * 16] = (bf16_t)(acc[hx][nc][r] * lf);
    }
  }
}

extern "C" void kernel_launch(void* const* d_in, const int* in_sizes, int n_in,
                              void* d_out, int out_size, void* d_ws, size_t ws_size,
                              hipStream_t stream) {
  (void)in_sizes; (void)n_in; (void)out_size; (void)ws_size;
  const float* x    = (const float*)d_in[0];
  const float* Wqkv = (const float*)d_in[1];
  const float* bqkv = (const float*)d_in[2];
  const float* Wout = (const float*)d_in[3];
  const float* bout = (const float*)d_in[4];
  float* out = (float*)d_out;

  char* ws = (char*)d_ws;
  bf16_t* xb    = (bf16_t*)(ws);                 //  8.39 MB  [4096][1024]
  bf16_t* wqkvT = (bf16_t*)(ws + 8388608);       //  6.29 MB  [3072][1024]
  bf16_t* woutT = (bf16_t*)(ws + 14680064);      //  2.10 MB  [1024][1024]
  bf16_t* qkv   = (bf16_t*)(ws + 16777216);      // 25.17 MB  [4096][3072] (V third unused)
  bf16_t* vT    = (bf16_t*)(ws + 41943040);      //  8.39 MB  [32][64][2048]
  bf16_t* aout  = (bf16_t*)(ws + 50331648);      //  8.39 MB  [4096][1024]

  cvt_f32_bf16<<<4096, 256, 0, stream>>>(x, xb, 1048576);
  trans_cvt<<<dim3(32, 96), dim3(32, 8), 0, stream>>>(Wqkv, wqkvT, 1024, 3072);
  trans_cvt<<<dim3(32, 32), dim3(32, 8), 0, stream>>>(Wout, woutT, 1024, 1024);
  gemm_bt<<<768, 256, 0, stream>>>(xb, wqkvT, bqkv, qkv, vT, nullptr, 4096, 3072, 1024, 1);
  attn_fwd<<<512, 256, 0, stream>>>(qkv, vT, aout);
  gemm_bt<<<256, 256, 0, stream>>>(aout, woutT, bout, nullptr, nullptr, out, 4096, 1024, 1024, 2);
}